// Round 2
// baseline (613.764 us; speedup 1.0000x reference)
//
#include <hip/hip_runtime.h>
#include <hip/hip_bf16.h>

// ---------------------------------------------------------------------------
// VersorAttention on MI355X (gfx950).
// Pipeline: cast x->bf16; per projection {build Wbig (sign-permuted w, bf16),
// GEMM, normalize}; transpose V; flash attention; final GEMM + normalize.
// All GEMMs: C(MxN) = A(MxK) . B(NxK)^T, bf16 inputs, fp32 accum (MFMA 16x16x32).
// Workspace: Xb(16M) Wb(8M, reused per projection) Qb Kb Vb Vt (16M each) = 88 MiB.
// Ao (attention out) aliases Xb (dead after V GEMM).
// ---------------------------------------------------------------------------

typedef unsigned short u16;
typedef unsigned short u16x8 __attribute__((ext_vector_type(8)));
typedef short          s16x8 __attribute__((ext_vector_type(8)));
typedef float          f32x4 __attribute__((ext_vector_type(4)));

#define B_DIM 2
#define S_DIM 2048
#define D_DIM 64
#define NH    8
#define HD    256          // head feature = (D/NH)*32
#define F_DIM 2048         // D*32
#define TOK   4096         // B*S

// blade lane ordering: sorted by (grade, mask)
__constant__ int LANE_MASK[32] = {
    0,
    1, 2, 4, 8, 16,
    3, 5, 6, 9, 10, 12, 17, 18, 20, 24,
    7, 11, 13, 14, 19, 21, 22, 25, 26, 28,
    15, 23, 27, 29, 30,
    31};
__constant__ int MASK_LANE[32] = {
    0, 1, 2, 6, 3, 7, 8, 16, 4, 9, 10, 17, 11, 18, 19, 26,
    5, 12, 13, 20, 14, 21, 22, 27, 15, 23, 24, 28, 25, 29, 30, 31};

__device__ __forceinline__ float gp_sign(int a, int b) {
  int swaps = 0;
  int aa = a >> 1;
  while (aa) { swaps += __popc(aa & b); aa >>= 1; }
  float s = (swaps & 1) ? -1.0f : 1.0f;
  if (a & b & 16) s = -s;   // e5*e5 = -1 (bit 4); e1..e4 square to +1
  return s;
}

__device__ __forceinline__ u16 f2bf(float f) {
  unsigned u = __float_as_uint(f);
  u += 0x7fffu + ((u >> 16) & 1u);   // round-to-nearest-even
  return (u16)(u >> 16);
}

__device__ __forceinline__ f32x4 mfma16(s16x8 a, s16x8 b, f32x4 c) {
  return __builtin_amdgcn_mfma_f32_16x16x32_bf16(a, b, c, 0, 0, 0);
}

// ---------------------------------------------------------------------------
// x (fp32) -> bf16
__global__ __launch_bounds__(256) void k_cast(const float* __restrict__ x,
                                              u16* __restrict__ xb) {
  int i = blockIdx.x * 256 + threadIdx.x;   // processes 8 elements
  const float4* x4 = (const float4*)x;
  float4 a = x4[2 * i], b = x4[2 * i + 1];
  u16x8 r;
  r[0] = f2bf(a.x); r[1] = f2bf(a.y); r[2] = f2bf(a.z); r[3] = f2bf(a.w);
  r[4] = f2bf(b.x); r[5] = f2bf(b.y); r[6] = f2bf(b.z); r[7] = f2bf(b.w);
  *(u16x8*)&xb[8 * i] = r;
}

// ---------------------------------------------------------------------------
// W[(o*32+k)*2048 + i*32+l] = gp_sign(mask_k^mask_l, mask_l) * w[o,i,j]
//   with mask_j = mask_k ^ mask_l  (gp table is one-hot in output blade).
__global__ __launch_bounds__(256) void k_buildw(const float* __restrict__ w,
                                                u16* __restrict__ W) {
  __shared__ float wvals[32];
  __shared__ int   jt[1024];
  __shared__ float st[1024];
  const int o = blockIdx.x >> 6, i = blockIdx.x & 63;
  const int tid = threadIdx.x;
  for (int e = tid; e < 1024; e += 256) {
    int k = e >> 5, l = e & 31;
    int mk = LANE_MASK[k], ml = LANE_MASK[l];
    int mj = mk ^ ml;
    jt[e] = MASK_LANE[mj];
    st[e] = gp_sign(mj, ml);
  }
  if (tid < 32) wvals[tid] = w[(o * D_DIM + i) * 32 + tid];
  __syncthreads();
  for (int e = tid; e < 1024; e += 256) {
    int k = e >> 5, l = e & 31;
    size_t off = (size_t)(o * 32 + k) * F_DIM + i * 32 + l;
    W[off] = f2bf(st[e] * wvals[jt[e]]);
  }
}

// ---------------------------------------------------------------------------
// C(MxN fp32) = A(MxK bf16, row-major) . B(NxK bf16, row-major)^T
// 128x128 tile, BK=64, 4 waves (2x2), each wave 64x64 (4x4 frags of 16x16).
#define LDT 72   // 64 + 8 pad: breaks the 128B-stride bank conflict (2-way, free)
__global__ __launch_bounds__(256) void k_gemm_bt(const u16* __restrict__ A,
                                                 const u16* __restrict__ B,
                                                 float* __restrict__ C,
                                                 int M, int N, int K) {
  __shared__ u16 As[128 * LDT];
  __shared__ u16 Bs[128 * LDT];
  const int tid = threadIdx.x;
  const int wid = tid >> 6, lane = tid & 63;
  const int row0 = blockIdx.y * 128, col0 = blockIdx.x * 128;
  const int wm = (wid >> 1) * 64, wn = (wid & 1) * 64;
  const int lr = lane & 15, lk = (lane >> 4) * 8;

  f32x4 acc[4][4];
#pragma unroll
  for (int m = 0; m < 4; ++m)
#pragma unroll
    for (int n = 0; n < 4; ++n) acc[m][n] = (f32x4)0.0f;

  for (int k0 = 0; k0 < K; k0 += 64) {
#pragma unroll
    for (int it = 0; it < 4; ++it) {
      int c = tid + it * 256;          // 0..1023 chunks of 8 elems
      int r = c >> 3, cg = (c & 7) * 8;
      *(u16x8*)&As[r * LDT + cg] = *(const u16x8*)&A[(size_t)(row0 + r) * K + k0 + cg];
      *(u16x8*)&Bs[r * LDT + cg] = *(const u16x8*)&B[(size_t)(col0 + r) * K + k0 + cg];
    }
    __syncthreads();
#pragma unroll
    for (int ks = 0; ks < 64; ks += 32) {
      s16x8 af[4], bf[4];
#pragma unroll
      for (int m = 0; m < 4; ++m)
        af[m] = *(const s16x8*)&As[(wm + m * 16 + lr) * LDT + ks + lk];
#pragma unroll
      for (int n = 0; n < 4; ++n)
        bf[n] = *(const s16x8*)&Bs[(wn + n * 16 + lr) * LDT + ks + lk];
#pragma unroll
      for (int m = 0; m < 4; ++m)
#pragma unroll
        for (int n = 0; n < 4; ++n)
          acc[m][n] = mfma16(af[m], bf[n], acc[m][n]);
    }
    __syncthreads();
  }
  // C/D layout: col = lane&15, row = (lane>>4)*4 + reg  [verified m89/m91]
#pragma unroll
  for (int m = 0; m < 4; ++m)
#pragma unroll
    for (int n = 0; n < 4; ++n) {
      int row = row0 + wm + m * 16 + (lane >> 4) * 4;
      int col = col0 + wn + n * 16 + lr;
#pragma unroll
      for (int r = 0; r < 4; ++r)
        C[(size_t)(row + r) * N + col] = acc[m][n][r];
    }
}

// ---------------------------------------------------------------------------
// per-32-lane multivector normalize.  MODE 0: bf16 out; MODE 1: bf16 out with
// sig[k]*rsqrt(hd) folded (for Q); MODE 2: fp32 in-place (final output).
template <int MODE>
__global__ __launch_bounds__(256) void k_norm(const float* __restrict__ pre,
                                              u16* __restrict__ outb,
                                              float* __restrict__ outf) {
  int i = blockIdx.x * 256 + threadIdx.x;
  float v = pre[i];
  float ss = v * v;
  ss += __shfl_xor(ss, 1);
  ss += __shfl_xor(ss, 2);
  ss += __shfl_xor(ss, 4);
  ss += __shfl_xor(ss, 8);
  ss += __shfl_xor(ss, 16);
  float inv = 1.0f / sqrtf(ss + 1e-6f);
  if (MODE == 0) {
    outb[i] = f2bf(v * inv);
  } else if (MODE == 1) {
    int lane32 = threadIdx.x & 31;
    int m = LANE_MASK[lane32];
    float sg = gp_sign(m, m);              // blade signature
    outb[i] = f2bf(v * inv * sg * 0.35355339059327373f);  // * 1/sqrt(hd)
  } else {
    outf[i] = v * inv;
  }
}

// ---------------------------------------------------------------------------
// batch-2 2048x2048 transpose (for V^T): out[b][f][s] = in[b][s][f]
__global__ __launch_bounds__(256) void k_transpose(const u16* __restrict__ in,
                                                   u16* __restrict__ out) {
  __shared__ u16 tile[32][33];
  int bz = blockIdx.z;
  int s0 = blockIdx.y * 32, f0 = blockIdx.x * 32;
  int tx = threadIdx.x, ty = threadIdx.y;
  size_t base = (size_t)bz * F_DIM * S_DIM;
#pragma unroll
  for (int j = 0; j < 32; j += 8)
    tile[ty + j][tx] = in[base + (size_t)(s0 + ty + j) * F_DIM + f0 + tx];
  __syncthreads();
#pragma unroll
  for (int j = 0; j < 32; j += 8)
    out[base + (size_t)(f0 + ty + j) * S_DIM + s0 + tx] = tile[tx][ty + j];
}

// ---------------------------------------------------------------------------
// Flash attention fwd.  Block = 4 waves; block owns (b, h, 128 q-rows); each
// wave owns 32 q-rows.  kv-tiles of 32.  K and V^T staged in padded LDS.
// Q (sig & 1/sqrt(hd) pre-folded) lives in registers.
__global__ __launch_bounds__(256) void k_attn(const u16* __restrict__ qb,
                                              const u16* __restrict__ kb,
                                              const u16* __restrict__ vt,
                                              u16* __restrict__ ao) {
  __shared__ u16 Ks[32][264];    // [kv][feat]  (256+8 pad)
  __shared__ u16 Vts[256][40];   // [feat][kv]  (32+8 pad)
  __shared__ u16 Ps[4][32][40];  // per-wave P tile [q][kv]
  const int tid = threadIdx.x, wid = tid >> 6, lane = tid & 63;
  const int blk = blockIdx.x;
  const int qblk = blk & 15, bh = blk >> 4;
  const int b = bh >> 3, h = bh & 7;
  const int lr = lane & 15, lk = (lane >> 4) * 8;
  const int q0 = qblk * 128 + wid * 32;

  // Q fragments: 2 row-frags x 8 k-chunks
  u16x8 qf[2][8];
#pragma unroll
  for (int m = 0; m < 2; ++m)
#pragma unroll
    for (int c = 0; c < 8; ++c)
      qf[m][c] = *(const u16x8*)&qb[(size_t)(b * S_DIM + q0 + m * 16 + lr) * F_DIM +
                                    h * HD + c * 32 + lk];

  float mrow[2][4], lsum[2][4];
#pragma unroll
  for (int m = 0; m < 2; ++m)
#pragma unroll
    for (int r = 0; r < 4; ++r) { mrow[m][r] = -1e30f; lsum[m][r] = 0.0f; }
  f32x4 oacc[2][16];
#pragma unroll
  for (int m = 0; m < 2; ++m)
#pragma unroll
    for (int d = 0; d < 16; ++d) oacc[m][d] = (f32x4)0.0f;

  for (int kv0 = 0; kv0 < S_DIM; kv0 += 32) {
    // stage K tile [32][256] and Vt tile [256][32]
#pragma unroll
    for (int it = 0; it < 4; ++it) {
      int c = tid + it * 256;
      {
        int r = c >> 5, cg = (c & 31) * 8;
        *(u16x8*)&Ks[r][cg] =
            *(const u16x8*)&kb[(size_t)(b * S_DIM + kv0 + r) * F_DIM + h * HD + cg];
      }
      {
        int r = c >> 2, cg = (c & 3) * 8;
        *(u16x8*)&Vts[r][cg] =
            *(const u16x8*)&vt[(size_t)(b * F_DIM + h * HD + r) * S_DIM + kv0 + cg];
      }
    }
    __syncthreads();

    // S = Q . K^T   (2 row-frags x 2 kv-col-frags)
    f32x4 sacc[2][2];
#pragma unroll
    for (int m = 0; m < 2; ++m)
#pragma unroll
      for (int n = 0; n < 2; ++n) sacc[m][n] = (f32x4)0.0f;
#pragma unroll
    for (int c = 0; c < 8; ++c) {
      s16x8 kf0 = *(const s16x8*)&Ks[lr][c * 32 + lk];
      s16x8 kf1 = *(const s16x8*)&Ks[16 + lr][c * 32 + lk];
#pragma unroll
      for (int m = 0; m < 2; ++m) {
        s16x8 a = *(const s16x8*)&qf[m][c];
        sacc[m][0] = mfma16(a, kf0, sacc[m][0]);
        sacc[m][1] = mfma16(a, kf1, sacc[m][1]);
      }
    }

    // online softmax (rows live in 16-lane groups: row = (lane>>4)*4 + r)
#pragma unroll
    for (int m = 0; m < 2; ++m) {
#pragma unroll
      for (int r = 0; r < 4; ++r) {
        float smax = fmaxf(sacc[m][0][r], sacc[m][1][r]);
        smax = fmaxf(smax, __shfl_xor(smax, 1));
        smax = fmaxf(smax, __shfl_xor(smax, 2));
        smax = fmaxf(smax, __shfl_xor(smax, 4));
        smax = fmaxf(smax, __shfl_xor(smax, 8));
        float mold = mrow[m][r];
        float mnew = fmaxf(mold, smax);
        mrow[m][r] = mnew;
        float alpha = expf(mold - mnew);
        float p0 = expf(sacc[m][0][r] - mnew);
        float p1 = expf(sacc[m][1][r] - mnew);
        int prow = m * 16 + (lane >> 4) * 4 + r;
        Ps[wid][prow][lr] = f2bf(p0);
        Ps[wid][prow][16 + lr] = f2bf(p1);
        float ps = p0 + p1;
        ps += __shfl_xor(ps, 1);
        ps += __shfl_xor(ps, 2);
        ps += __shfl_xor(ps, 4);
        ps += __shfl_xor(ps, 8);
        lsum[m][r] = lsum[m][r] * alpha + ps;
#pragma unroll
        for (int d = 0; d < 16; ++d) oacc[m][d][r] *= alpha;
      }
    }

    // O += P . V   (P via per-wave LDS round-trip to reach A-frag layout)
    s16x8 pf0 = *(const s16x8*)&Ps[wid][lr][lk];
    s16x8 pf1 = *(const s16x8*)&Ps[wid][16 + lr][lk];
#pragma unroll
    for (int d0 = 0; d0 < 16; ++d0) {
      s16x8 vf = *(const s16x8*)&Vts[d0 * 16 + lr][lk];
      oacc[0][d0] = mfma16(pf0, vf, oacc[0][d0]);
      oacc[1][d0] = mfma16(pf1, vf, oacc[1][d0]);
    }
    __syncthreads();
  }

  // epilogue: divide by denominator, write bf16 in (B,S,D,32) layout
#pragma unroll
  for (int m = 0; m < 2; ++m)
#pragma unroll
    for (int r = 0; r < 4; ++r) {
      float inv = 1.0f / lsum[m][r];
      int row = q0 + m * 16 + (lane >> 4) * 4 + r;
#pragma unroll
      for (int d0 = 0; d0 < 16; ++d0)
        ao[(size_t)(b * S_DIM + row) * F_DIM + h * HD + d0 * 16 + lr] =
            f2bf(oacc[m][d0][r] * inv);
    }
}

// ---------------------------------------------------------------------------
extern "C" void kernel_launch(void* const* d_in, const int* in_sizes, int n_in,
                              void* d_out, int out_size, void* d_ws, size_t ws_size,
                              hipStream_t stream) {
  const float* x  = (const float*)d_in[0];
  const float* wq = (const float*)d_in[1];
  const float* wk = (const float*)d_in[2];
  const float* wv = (const float*)d_in[3];
  const float* wo = (const float*)d_in[4];

  char* ws = (char*)d_ws;
  const size_t SZ_XB = (size_t)TOK * F_DIM * sizeof(u16);    // 16 MiB
  const size_t SZ_W  = (size_t)F_DIM * F_DIM * sizeof(u16);  // 8 MiB
  u16* Xb = (u16*)(ws);
  u16* Wb = (u16*)(ws + SZ_XB);            // reused for each projection
  u16* Qb = (u16*)(ws + SZ_XB + SZ_W);
  u16* Kb = Qb + (size_t)TOK * F_DIM;
  u16* Vb = Kb + (size_t)TOK * F_DIM;
  u16* Vt = Vb + (size_t)TOK * F_DIM;
  u16* Ao = Xb;                            // aliases Xb (dead after V GEMM)
  float* pre = (float*)d_out;  // d_out doubles as fp32 pre-normalize scratch

  dim3 gemm_grid(F_DIM / 128, TOK / 128);  // (16, 32)
  const int norm_blocks = TOK * F_DIM / 256;
  const int bw_blocks = D_DIM * D_DIM;

  k_cast<<<TOK * F_DIM / (256 * 8), 256, 0, stream>>>(x, Xb);

  k_buildw<<<bw_blocks, 256, 0, stream>>>(wq, Wb);
  k_gemm_bt<<<gemm_grid, 256, 0, stream>>>(Xb, Wb, pre, TOK, F_DIM, F_DIM);
  k_norm<1><<<norm_blocks, 256, 0, stream>>>(pre, Qb, nullptr);

  k_buildw<<<bw_blocks, 256, 0, stream>>>(wk, Wb);
  k_gemm_bt<<<gemm_grid, 256, 0, stream>>>(Xb, Wb, pre, TOK, F_DIM, F_DIM);
  k_norm<0><<<norm_blocks, 256, 0, stream>>>(pre, Kb, nullptr);

  k_buildw<<<bw_blocks, 256, 0, stream>>>(wv, Wb);
  k_gemm_bt<<<gemm_grid, 256, 0, stream>>>(Xb, Wb, pre, TOK, F_DIM, F_DIM);
  k_norm<0><<<norm_blocks, 256, 0, stream>>>(pre, Vb, nullptr);

  k_transpose<<<dim3(64, 64, 2), dim3(32, 8), 0, stream>>>(Vb, Vt);

  k_attn<<<B_DIM * NH * (S_DIM / 128), 256, 0, stream>>>(Qb, Kb, Vt, Ao);

  k_buildw<<<bw_blocks, 256, 0, stream>>>(wo, Wb);
  k_gemm_bt<<<gemm_grid, 256, 0, stream>>>(Ao, Wb, pre, TOK, F_DIM, F_DIM);
  k_norm<2><<<norm_blocks, 256, 0, stream>>>(pre, nullptr, (float*)d_out);
}

// Round 3
// 526.300 us; speedup vs baseline: 1.1662x; 1.1662x over previous
//
#include <hip/hip_runtime.h>
#include <hip/hip_bf16.h>

// ---------------------------------------------------------------------------
// VersorAttention on MI355X (gfx950).
// cast x->bf16; per projection {buildW, m97-style GEMM with fused
// normalize epilogue (Q: xsig*scale*log2e; V: transposed write)}; flash
// attention (4 waves x 16 q-rows, KV=64, defer-max, exp2); final GEMM with
// fused fp32 normalize -> d_out.
// ---------------------------------------------------------------------------

typedef unsigned short u16;
typedef unsigned short u16x8 __attribute__((ext_vector_type(8)));
typedef unsigned short u16x4 __attribute__((ext_vector_type(4)));
typedef short          s16x8 __attribute__((ext_vector_type(8)));
typedef float          f32x4 __attribute__((ext_vector_type(4)));

#define B_DIM 2
#define S_DIM 2048
#define D_DIM 64
#define NH    8
#define HD    256          // head feature = (D/NH)*32
#define F_DIM 2048         // D*32
#define TOK   4096         // B*S

// blade lane ordering: sorted by (grade, mask)
__constant__ int LANE_MASK[32] = {
    0,
    1, 2, 4, 8, 16,
    3, 5, 6, 9, 10, 12, 17, 18, 20, 24,
    7, 11, 13, 14, 19, 21, 22, 25, 26, 28,
    15, 23, 27, 29, 30,
    31};
__constant__ int MASK_LANE[32] = {
    0, 1, 2, 6, 3, 7, 8, 16, 4, 9, 10, 17, 11, 18, 19, 26,
    5, 12, 13, 20, 14, 21, 22, 27, 15, 23, 24, 28, 25, 29, 30, 31};

__device__ __forceinline__ float gp_sign(int a, int b) {
  int swaps = 0;
  int aa = a >> 1;
  while (aa) { swaps += __popc(aa & b); aa >>= 1; }
  float s = (swaps & 1) ? -1.0f : 1.0f;
  if (a & b & 16) s = -s;   // e5*e5 = -1 (bit 4); e1..e4 square to +1
  return s;
}

__device__ __forceinline__ u16 f2bf(float f) {
  unsigned u = __float_as_uint(f);
  u += 0x7fffu + ((u >> 16) & 1u);   // round-to-nearest-even
  return (u16)(u >> 16);
}

__device__ __forceinline__ f32x4 mfma16(s16x8 a, s16x8 b, f32x4 c) {
  return __builtin_amdgcn_mfma_f32_16x16x32_bf16(a, b, c, 0, 0, 0);
}

// async global->LDS, 16B per lane; LDS dest = wave-uniform base + lane*16
__device__ __forceinline__ void gload16(const u16* g, u16* l) {
  __builtin_amdgcn_global_load_lds(
      (const __attribute__((address_space(1))) void*)g,
      (__attribute__((address_space(3))) void*)l, 16, 0, 0);
}

// ---------------------------------------------------------------------------
// x (fp32) -> bf16
__global__ __launch_bounds__(256) void k_cast(const float* __restrict__ x,
                                              u16* __restrict__ xb) {
  int i = blockIdx.x * 256 + threadIdx.x;   // 8 elements each
  const float4* x4 = (const float4*)x;
  float4 a = x4[2 * i], b = x4[2 * i + 1];
  u16x8 r;
  r[0] = f2bf(a.x); r[1] = f2bf(a.y); r[2] = f2bf(a.z); r[3] = f2bf(a.w);
  r[4] = f2bf(b.x); r[5] = f2bf(b.y); r[6] = f2bf(b.z); r[7] = f2bf(b.w);
  *(u16x8*)&xb[8 * i] = r;
}

// ---------------------------------------------------------------------------
// W[(o*32+k)*2048 + i*32+l] = gp_sign(mask_k^mask_l, mask_l) * w[o,i,j],
// mask_j = mask_k ^ mask_l  (gp table one-hot in output blade).
__global__ __launch_bounds__(256) void k_buildw(const float* __restrict__ w,
                                                u16* __restrict__ W) {
  __shared__ float wvals[32];
  __shared__ int   jt[1024];
  __shared__ float st[1024];
  const int o = blockIdx.x >> 6, i = blockIdx.x & 63;
  const int tid = threadIdx.x;
  for (int e = tid; e < 1024; e += 256) {
    int k = e >> 5, l = e & 31;
    int mk = LANE_MASK[k], ml = LANE_MASK[l];
    int mj = mk ^ ml;
    jt[e] = MASK_LANE[mj];
    st[e] = gp_sign(mj, ml);
  }
  if (tid < 32) wvals[tid] = w[(o * D_DIM + i) * 32 + tid];
  __syncthreads();
  for (int e = tid; e < 1024; e += 256) {
    int k = e >> 5, l = e & 31;
    size_t off = (size_t)(o * 32 + k) * F_DIM + i * 32 + l;
    W[off] = f2bf(st[e] * wvals[jt[e]]);
  }
}

// ---------------------------------------------------------------------------
// C(MxN) = A(MxK) . B(NxK)^T  with fused multivector-normalize epilogue.
// m97 structure: 128x128 tile, BK=64, linear LDS, global_load_lds width=16.
// MODE 0: bf16 out.  MODE 1: bf16 out * sig*scale*log2e (Q).
// MODE 2: fp32 out (final).  MODE 3: bf16 transposed out (V -> Vt[b][f][s]).
template <int MODE>
__global__ __launch_bounds__(256) void k_gemm_fused(const u16* __restrict__ A,
                                                    const u16* __restrict__ B,
                                                    u16* __restrict__ outb,
                                                    float* __restrict__ outf) {
  constexpr int K = F_DIM, N = F_DIM;
  __shared__ u16 As[128 * 64];
  __shared__ u16 Bs[128 * 64];
  const int tid = threadIdx.x;
  const int wid = tid >> 6, lane = tid & 63;
  const int row0 = blockIdx.y * 128, col0 = blockIdx.x * 128;
  const int wm = (wid >> 1) * 64, wn = (wid & 1) * 64;
  const int lr = lane & 15, lk = (lane >> 4) * 8;
  const int srow = lane >> 3, scol = (lane & 7) * 8;   // staging: 8 rows/wave

  f32x4 acc[4][4];
#pragma unroll
  for (int m = 0; m < 4; ++m)
#pragma unroll
    for (int n = 0; n < 4; ++n) acc[m][n] = (f32x4)0.0f;

  for (int k0 = 0; k0 < K; k0 += 64) {
#pragma unroll
    for (int it = 0; it < 4; ++it) {
      int c = it * 4 + wid;            // 16 chunks of 8 rows x 64 cols
      gload16(&A[(size_t)(row0 + c * 8 + srow) * K + k0 + scol], &As[c * 512]);
      gload16(&B[(size_t)(col0 + c * 8 + srow) * K + k0 + scol], &Bs[c * 512]);
    }
    __syncthreads();
#pragma unroll
    for (int ks = 0; ks < 64; ks += 32) {
      s16x8 af[4], bf[4];
#pragma unroll
      for (int m = 0; m < 4; ++m)
        af[m] = *(const s16x8*)&As[(wm + m * 16 + lr) * 64 + ks + lk];
#pragma unroll
      for (int n = 0; n < 4; ++n)
        bf[n] = *(const s16x8*)&Bs[(wn + n * 16 + lr) * 64 + ks + lk];
#pragma unroll
      for (int m = 0; m < 4; ++m)
#pragma unroll
        for (int n = 0; n < 4; ++n)
          acc[m][n] = mfma16(af[m], bf[n], acc[m][n]);
    }
    __syncthreads();
  }

  // epilogue: normalize each 32-lane multivector (cols [c32, c32+32) of a row)
  float sc0 = 1.0f, sc1 = 1.0f;
  if (MODE == 1) {
    const float qs = 0.35355339059327373f * 1.4426950408889634f;  // 1/sqrt(8)*log2e
    int m0 = LANE_MASK[lr], m1 = LANE_MASK[16 + lr];
    sc0 = gp_sign(m0, m0) * qs;
    sc1 = gp_sign(m1, m1) * qs;
  }
#pragma unroll
  for (int m = 0; m < 4; ++m) {
    int rowb = row0 + wm + m * 16 + (lane >> 4) * 4;
#pragma unroll
    for (int np = 0; np < 2; ++np) {
      int n0 = 2 * np, n1 = n0 + 1;
      int colb = col0 + wn + np * 32 + lr;
      f32x4 inv;
#pragma unroll
      for (int r = 0; r < 4; ++r) {
        float a0 = acc[m][n0][r], a1 = acc[m][n1][r];
        float s2 = a0 * a0 + a1 * a1;
        s2 += __shfl_xor(s2, 1);
        s2 += __shfl_xor(s2, 2);
        s2 += __shfl_xor(s2, 4);
        s2 += __shfl_xor(s2, 8);
        inv[r] = 1.0f / sqrtf(s2 + 1e-6f);
      }
      if (MODE == 3) {
        // V: write normalized, transposed: Vt[(b*F + f)*S + s]
        int bb = rowb >> 11, s0 = rowb & 2047;
        u16x4 p0, p1;
#pragma unroll
        for (int r = 0; r < 4; ++r) {
          p0[r] = f2bf(acc[m][n0][r] * inv[r]);
          p1[r] = f2bf(acc[m][n1][r] * inv[r]);
        }
        *(u16x4*)&outb[((size_t)bb * F_DIM + colb) * S_DIM + s0] = p0;
        *(u16x4*)&outb[((size_t)bb * F_DIM + colb + 16) * S_DIM + s0] = p1;
      } else {
#pragma unroll
        for (int r = 0; r < 4; ++r) {
          size_t o = (size_t)(rowb + r) * N + colb;
          if (MODE == 2) {
            outf[o]      = acc[m][n0][r] * inv[r];
            outf[o + 16] = acc[m][n1][r] * inv[r];
          } else {
            outb[o]      = f2bf(acc[m][n0][r] * inv[r] * sc0);
            outb[o + 16] = f2bf(acc[m][n1][r] * inv[r] * sc1);
          }
        }
      }
    }
  }
}

// ---------------------------------------------------------------------------
// Flash attention.  Block = 4 waves; block owns (b,h,64 q-rows); wave owns 16.
// KV-tile 64.  Scores arrive in log2 domain (log2e folded into Q).
// Defer-max (THR=8): skip O/l rescale while per-tile max growth is small.
__global__ __launch_bounds__(256) void k_attn(const u16* __restrict__ qb,
                                              const u16* __restrict__ kb,
                                              const u16* __restrict__ vt,
                                              u16* __restrict__ ao) {
  __shared__ u16 Ks[64][264];    // 33.8 KB  (row stride 132 banks == 4 mod 32)
  __shared__ u16 Vts[256][72];   // 36.9 KB  (row stride 36 banks == 4 mod 32)
  __shared__ u16 Ps[4][16][72];  //  9.2 KB  per-wave P
  const int tid = threadIdx.x, wid = tid >> 6, lane = tid & 63;
  // XCD-bijective remap: co-locate each (b,h)'s K/V (2 MB) on one XCD's L2
  const int rid = (blockIdx.x & 7) * 64 + (blockIdx.x >> 3);
  const int qblk = rid & 31, bh = rid >> 5;
  const int b = bh >> 3, h = bh & 7;
  const int lr = lane & 15, lk = (lane >> 4) * 8;
  const int q0 = qblk * 64 + wid * 16;

  u16x8 qf[8];
#pragma unroll
  for (int c = 0; c < 8; ++c)
    qf[c] = *(const u16x8*)&qb[(size_t)(b * S_DIM + q0 + lr) * F_DIM +
                               h * HD + c * 32 + lk];

  float mrow[4], lacc[4];
#pragma unroll
  for (int r = 0; r < 4; ++r) { mrow[r] = -1e30f; lacc[r] = 0.0f; }
  f32x4 oacc[16];
#pragma unroll
  for (int d = 0; d < 16; ++d) oacc[d] = (f32x4)0.0f;

  for (int kv0 = 0; kv0 < S_DIM; kv0 += 64) {
    // stage K [64][256] and Vt [256][64]
#pragma unroll
    for (int i = 0; i < 8; ++i) {
      int c = i * 256 + tid;
      {
        int r = c >> 5, off = (c & 31) * 8;
        *(u16x8*)&Ks[r][off] =
            *(const u16x8*)&kb[(size_t)(b * S_DIM + kv0 + r) * F_DIM + h * HD + off];
      }
      {
        int r = c >> 3, off = (c & 7) * 8;
        *(u16x8*)&Vts[r][off] =
            *(const u16x8*)&vt[((size_t)b * F_DIM + h * HD + r) * S_DIM + kv0 + off];
      }
    }
    __syncthreads();

    // S = Q . K^T : 16 rows x 64 cols (4 col-frags)
    f32x4 sacc[4];
#pragma unroll
    for (int n = 0; n < 4; ++n) sacc[n] = (f32x4)0.0f;
#pragma unroll
    for (int c = 0; c < 8; ++c) {
      s16x8 a = *(const s16x8*)&qf[c];
#pragma unroll
      for (int n = 0; n < 4; ++n) {
        s16x8 kf = *(const s16x8*)&Ks[n * 16 + lr][c * 32 + lk];
        sacc[n] = mfma16(a, kf, sacc[n]);
      }
    }

    // online softmax in log2 domain; rows = (lane>>4)*4 + r
    float pmax[4], need = 0.0f;
#pragma unroll
    for (int r = 0; r < 4; ++r) {
      float mx = fmaxf(fmaxf(sacc[0][r], sacc[1][r]), fmaxf(sacc[2][r], sacc[3][r]));
      mx = fmaxf(mx, __shfl_xor(mx, 1));
      mx = fmaxf(mx, __shfl_xor(mx, 2));
      mx = fmaxf(mx, __shfl_xor(mx, 4));
      mx = fmaxf(mx, __shfl_xor(mx, 8));
      pmax[r] = mx;
      need = fmaxf(need, mx - mrow[r]);
    }
    if (!__all(need <= 8.0f)) {
#pragma unroll
      for (int r = 0; r < 4; ++r) {
        float mnew = fmaxf(mrow[r], pmax[r]);
        float alpha = exp2f(mrow[r] - mnew);
        mrow[r] = mnew;
        lacc[r] *= alpha;
#pragma unroll
        for (int d = 0; d < 16; ++d) oacc[d][r] *= alpha;
      }
    }
#pragma unroll
    for (int n = 0; n < 4; ++n)
#pragma unroll
      for (int r = 0; r < 4; ++r) {
        float p = exp2f(sacc[n][r] - mrow[r]);
        lacc[r] += p;
        Ps[wid][(lane >> 4) * 4 + r][n * 16 + lr] = f2bf(p);
      }

    // O += P . V  (same-wave LDS round-trip; in-order DS keeps it safe)
#pragma unroll
    for (int ks = 0; ks < 2; ++ks) {
      s16x8 pf = *(const s16x8*)&Ps[wid][lr][ks * 32 + lk];
#pragma unroll
      for (int d0 = 0; d0 < 16; ++d0) {
        s16x8 vf = *(const s16x8*)&Vts[d0 * 16 + lr][ks * 32 + lk];
        oacc[d0] = mfma16(pf, vf, oacc[d0]);
      }
    }
    __syncthreads();
  }

  // epilogue: reduce distributed row-sums, divide, write bf16
#pragma unroll
  for (int r = 0; r < 4; ++r) {
    float s = lacc[r];
    s += __shfl_xor(s, 1);
    s += __shfl_xor(s, 2);
    s += __shfl_xor(s, 4);
    s += __shfl_xor(s, 8);
    float inv = 1.0f / s;
    int row = q0 + (lane >> 4) * 4 + r;
#pragma unroll
    for (int d0 = 0; d0 < 16; ++d0)
      ao[(size_t)(b * S_DIM + row) * F_DIM + h * HD + d0 * 16 + lr] =
          f2bf(oacc[d0][r] * inv);
  }
}

// ---------------------------------------------------------------------------
extern "C" void kernel_launch(void* const* d_in, const int* in_sizes, int n_in,
                              void* d_out, int out_size, void* d_ws, size_t ws_size,
                              hipStream_t stream) {
  const float* x  = (const float*)d_in[0];
  const float* wq = (const float*)d_in[1];
  const float* wk = (const float*)d_in[2];
  const float* wv = (const float*)d_in[3];
  const float* wo = (const float*)d_in[4];

  char* ws = (char*)d_ws;
  const size_t SZ_XB = (size_t)TOK * F_DIM * sizeof(u16);    // 16 MiB
  const size_t SZ_W  = (size_t)F_DIM * F_DIM * sizeof(u16);  // 8 MiB
  u16* Xb = (u16*)(ws);
  u16* Wb = (u16*)(ws + SZ_XB);            // reused per projection
  u16* Qb = (u16*)(ws + SZ_XB + SZ_W);
  u16* Kb = Qb + (size_t)TOK * F_DIM;
  u16* Vt = Kb + (size_t)TOK * F_DIM;      // V, normalized + transposed
  u16* Ao = Xb;                            // aliases Xb (dead after V GEMM)

  dim3 gemm_grid(F_DIM / 128, TOK / 128);  // (16, 32)
  const int bw_blocks = D_DIM * D_DIM;

  k_cast<<<TOK * F_DIM / (256 * 8), 256, 0, stream>>>(x, Xb);

  k_buildw<<<bw_blocks, 256, 0, stream>>>(wq, Wb);
  k_gemm_fused<1><<<gemm_grid, 256, 0, stream>>>(Xb, Wb, Qb, nullptr);

  k_buildw<<<bw_blocks, 256, 0, stream>>>(wk, Wb);
  k_gemm_fused<0><<<gemm_grid, 256, 0, stream>>>(Xb, Wb, Kb, nullptr);

  k_buildw<<<bw_blocks, 256, 0, stream>>>(wv, Wb);
  k_gemm_fused<3><<<gemm_grid, 256, 0, stream>>>(Xb, Wb, Vt, nullptr);

  k_attn<<<B_DIM * NH * (S_DIM / 64), 256, 0, stream>>>(Qb, Kb, Vt, Ao);

  k_buildw<<<bw_blocks, 256, 0, stream>>>(wo, Wb);
  k_gemm_fused<2><<<gemm_grid, 256, 0, stream>>>(Ao, Wb, nullptr, (float*)d_out);
}